// Round 5
// baseline (2220.187 us; speedup 1.0000x reference)
//
#include <hip/hip_runtime.h>

// Problem constants
constexpr int B = 64, T = 1024, D = 128, H = 256;
// RNN partition: 64 groups (1 batch each) x 4 blocks of 1024 threads.
// Each block owns 64 units; 16 lanes (k-chunks) per unit -> 72 weight floats/thread.
constexpr int NG = 64;   // groups
constexpr int GK = 4;    // blocks per group
constexpr int UO = 64;   // hidden units owned per block
constexpr int CS = 20;   // hdec chunk stride in floats (16 data + 4 skew; 16B-aligned)

__device__ __forceinline__ float sigmoidf_(float v) {
    return 1.f / (1.f + __expf(-v));
}
__device__ __forceinline__ float tanhf_(float v) {
    float e2 = __expf(2.f * v);
    return 1.f - 2.f / (e2 + 1.f);
}

// ---------------- P1: per-(b,d) scan over t (prefetch-unrolled) ----------------
__global__ __launch_bounds__(64) void prep_scan(
    const float* __restrict__ x, const int* __restrict__ mask,
    const float* __restrict__ ts, const float* __restrict__ it0,
    float* __restrict__ ffill, float* __restrict__ idelta,
    float* __restrict__ mean, float* __restrict__ tdlv)
{
    const int b = blockIdx.x;
    const int d = blockIdx.y * 64 + threadIdx.x;
    float prev_x = 0.f, prev_td = 0.f, osum = 0.f, mcnt = 0.f;
    float prev_ts = it0[b];               // init_time is (1,B) -> flat[b]
    const int baseT = b * T;
    constexpr int U = 16;
    for (int t0 = 0; t0 < T; t0 += U) {
        float xv[U]; int mv[U]; float tsv[U];
        #pragma unroll
        for (int u = 0; u < U; ++u) {
            const int idx = (baseT + t0 + u) * D + d;
            xv[u] = x[idx];
            mv[u] = mask[idx];
        }
        #pragma unroll
        for (int u = 0; u < U; ++u) tsv[u] = ts[baseT + t0 + u];
        #pragma unroll
        for (int u = 0; u < U; ++u) {
            const float td = tsv[u] - prev_ts;
            prev_ts = tsv[u];
            const int idx = (baseT + t0 + u) * D + d;
            if (!mv[u]) { prev_x = xv[u]; osum += xv[u]; } else { mcnt += 1.f; }
            prev_td += td;
            ffill[idx]  = prev_x;
            idelta[idx] = prev_td;
            if (!mv[u]) prev_td = 0.f;
            if (d == 0) tdlv[baseT + t0 + u] = logf(fminf(fmaxf(td, 0.f), 1000.f));
        }
    }
    mean[b * D + d] = osum / fmaxf(mcnt, 1.f);
}

// ---------------- P2: imputation matvec ----------------
constexpr int ROWS = 64;   // (b,t) rows per block
__global__ __launch_bounds__(256) void fill_kernel(
    const float* __restrict__ x, const int* __restrict__ mask,
    const float* __restrict__ ffill, const float* __restrict__ idelta,
    const float* __restrict__ mean, const float* __restrict__ idw,
    const float* __restrict__ idb, float* __restrict__ xf)
{
    __shared__ float widw[128 * 129];   // padded: conflict-free
    __shared__ float ide[2][128];
    const int tid = threadIdx.x;
    for (int i = tid; i < 128 * 128; i += 256)
        widw[(i >> 7) * 129 + (i & 127)] = idw[i];
    __syncthreads();
    const int p = tid >> 7, d = tid & 127;
    const float bias = idb[d];
    const int row0 = blockIdx.x * ROWS;
    for (int r = 0; r < ROWS; r += 2) {
        const int rowp = row0 + r + p;    // b*T + t
        const int idx = rowp * D + d;
        ide[p][d] = fminf(fmaxf(idelta[idx] - 1.f, 0.f), 1000.f);
        __syncthreads();
        float acc = bias;
        #pragma unroll
        for (int k = 0; k < 128; ++k)
            acc = fmaf(ide[p][k], widw[d * 129 + k], acc);
        float fw = __expf(-fmaxf(acc, 0.f));
        float filled = ffill[idx] * fw + (1.f - fw) * mean[(rowp >> 10) * D + d];
        xf[idx] = mask[idx] ? filled : x[idx];
        __syncthreads();
    }
}

// ---------------- P3: persistent grouped GRU-D recurrence ----------------
// 64 independent groups (1 batch each) of 4 blocks x 1024 threads. Fence-free
// tagged 64-bit LLC exchange (tag = step+1 | f32 bits), parity double-buffered.
// One barrier per step; hdec parity-buffered with skewed chunk stride (CS=20,
// 16 chunks of 16 floats) -> worst 2-way bank aliasing on reads/writes (free).
__global__ __launch_bounds__(1024, 4) void rnn_kernel(
    const float* __restrict__ xf, const float* __restrict__ tdlv,
    const float* __restrict__ w_ih, const float* __restrict__ w_hh,
    const float* __restrict__ b_ih, const float* __restrict__ b_hh,
    const float* __restrict__ hdw, const float* __restrict__ hdb,
    unsigned long long* __restrict__ hx, float* __restrict__ out)
{
    const int tid = threadIdx.x;
    const int g  = blockIdx.x & (NG - 1);   // group = batch
    const int kb = blockIdx.x >> 6;         // owns units [kb*64, kb*64+64)
    const int u_loc = tid >> 4;             // 0..63
    const int kc = tid & 15;                // k-chunk 0..15
    const int row = kb * UO + u_loc;        // owned hidden unit
    const int b = g;                        // batch

    // Weight-stationary register slices: gh chunk = 16, gi chunk = 8
    float whr[16], whz[16], whn[16];
    #pragma unroll
    for (int j = 0; j < 16; ++j) {
        whr[j] = w_hh[(row        ) * H + kc * 16 + j];
        whz[j] = w_hh[(row +     H) * H + kc * 16 + j];
        whn[j] = w_hh[(row + 2 * H) * H + kc * 16 + j];
    }
    float wir[8], wiz[8], win_[8];
    #pragma unroll
    for (int j = 0; j < 8; ++j) {
        wir[j]  = w_ih[(row        ) * D + kc * 8 + j];
        wiz[j]  = w_ih[(row +     H) * D + kc * 8 + j];
        win_[j] = w_ih[(row + 2 * H) * D + kc * 8 + j];
    }
    // Staging role: threads 0..255 stage unit k = tid
    const bool stager = (tid < H);
    const bool ownk = stager && ((tid >> 6) == kb);
    const float hdwk = stager ? hdw[tid] : 0.f;
    const float hdbk = stager ? hdb[tid] : 0.f;
    const float hdwo = hdw[row];            // decay params for owned unit
    const float hdbo = hdb[row];
    float br = 0.f, bz = 0.f, bnx = 0.f, bnh = 0.f;
    if (kc == 0) {
        br  = b_ih[row] + b_hh[row];
        bz  = b_ih[H + row] + b_hh[H + row];
        bnx = b_ih[2 * H + row];
        bnh = b_hh[2 * H + row];
    }

    __shared__ float hdec[2][16 * CS];  // decayed h, parity buffered, skewed
    for (int i = tid; i < 2 * 16 * CS; i += 1024)
        ((float*)hdec)[i] = 0.f;        // h0 = 0 (decayed 0 is 0)
    __syncthreads();

    const float* tdlb = tdlv + b * T;

    for (int t = 0; t < T; ++t) {
        const int par = t & 1;

        // ---- (a) prefetch-probe the remote tag word (hide under gi) ----
        const bool need = (t > 0) && stager && !ownk;
        const unsigned long long* slot =
            hx + (size_t)((t - 1) & 1) * (B * H) + b * H + tid;
        unsigned long long v = 0;
        if (need)
            v = __hip_atomic_load(slot, __ATOMIC_RELAXED, __HIP_MEMORY_SCOPE_AGENT);

        // ---- (b) gi partials: independent of h ----
        const float4* xp4 = (const float4*)(xf + (size_t)(b * T + t) * D + kc * 8);
        float a0 = 0.f, a1 = 0.f, a2 = 0.f;
        #pragma unroll
        for (int i = 0; i < 2; ++i) {
            float4 xq = xp4[i];
            a0 = fmaf(wir[4*i  ], xq.x, a0); a1 = fmaf(wiz[4*i  ], xq.x, a1); a2 = fmaf(win_[4*i  ], xq.x, a2);
            a0 = fmaf(wir[4*i+1], xq.y, a0); a1 = fmaf(wiz[4*i+1], xq.y, a1); a2 = fmaf(win_[4*i+1], xq.y, a2);
            a0 = fmaf(wir[4*i+2], xq.z, a0); a1 = fmaf(wiz[4*i+2], xq.z, a1); a2 = fmaf(win_[4*i+2], xq.z, a2);
            a0 = fmaf(wir[4*i+3], xq.w, a0); a1 = fmaf(wiz[4*i+3], xq.w, a1); a2 = fmaf(win_[4*i+3], xq.w, a2);
        }

        // ---- (c) finish poll + stage decayed remote h into LDS ----
        if (need) {
            while ((unsigned)(v >> 32) != (unsigned)t)
                v = __hip_atomic_load(slot, __ATOMIC_RELAXED, __HIP_MEMORY_SCOPE_AGENT);
            float hv = __uint_as_float((unsigned)v);
            float dec = __expf(-fmaxf(tdlb[t] * hdwk + hdbk, 0.f));
            hdec[par][(tid >> 4) * CS + (tid & 15)] = hv * dec;
        }
        __syncthreads();

        // ---- (d) gh partials from LDS (skewed chunks) ----
        float a3 = 0.f;
        const float4* hp4 = (const float4*)(&hdec[par][kc * CS]);
        #pragma unroll
        for (int i = 0; i < 4; ++i) {
            float4 hq = hp4[i];
            a0 = fmaf(whr[4*i  ], hq.x, a0); a1 = fmaf(whz[4*i  ], hq.x, a1); a3 = fmaf(whn[4*i  ], hq.x, a3);
            a0 = fmaf(whr[4*i+1], hq.y, a0); a1 = fmaf(whz[4*i+1], hq.y, a1); a3 = fmaf(whn[4*i+1], hq.y, a3);
            a0 = fmaf(whr[4*i+2], hq.z, a0); a1 = fmaf(whz[4*i+2], hq.z, a1); a3 = fmaf(whn[4*i+2], hq.z, a3);
            a0 = fmaf(whr[4*i+3], hq.w, a0); a1 = fmaf(whz[4*i+3], hq.w, a1); a3 = fmaf(whn[4*i+3], hq.w, a3);
        }

        // ---- (e) butterfly reduce over the 16 k-chunk lanes ----
        #pragma unroll
        for (int m = 1; m < 16; m <<= 1) {
            a0 += __shfl_xor(a0, m, 64);
            a1 += __shfl_xor(a1, m, 64);
            a2 += __shfl_xor(a2, m, 64);
            a3 += __shfl_xor(a3, m, 64);
        }

        // ---- (f) owner-lane epilogue: hnew, publish first, then stores ----
        if (kc == 0) {
            float hd = hdec[par][(row >> 4) * CS + (row & 15)];
            float r = sigmoidf_(a0 + br);
            float z = sigmoidf_(a1 + bz);
            float n = tanhf_(a2 + bnx + r * (a3 + bnh));
            float hnew = (1.f - z) * n + z * hd;
            // publish to LLC (tag = t+1) -- first, so the store leaves now
            __hip_atomic_store(hx + (size_t)par * (B * H) + b * H + row,
                               (((unsigned long long)(unsigned)(t + 1)) << 32) |
                               (unsigned long long)__float_as_uint(hnew),
                               __ATOMIC_RELAXED, __HIP_MEMORY_SCOPE_AGENT);
            // pre-stage own unit's decayed h for step t+1 (readers of
            // hdec[par^1] only run after next step's barrier)
            if (t + 1 < T) {
                float dec = __expf(-fmaxf(tdlb[t + 1] * hdwo + hdbo, 0.f));
                hdec[par ^ 1][(row >> 4) * CS + (row & 15)] = hnew * dec;
            }
            out[(size_t)(b * T + t) * H + row] = hnew;
            if (t == T - 1)
                out[(size_t)B * T * H + b * H + row] = hnew;
        }
        // no end-of-step barrier: parity buffering + next step's barrier
        // order all hdec writes before their reads.
    }
}

extern "C" void kernel_launch(void* const* d_in, const int* in_sizes, int n_in,
                              void* d_out, int out_size, void* d_ws, size_t ws_size,
                              hipStream_t stream) {
    (void)in_sizes; (void)n_in; (void)out_size; (void)ws_size;
    const float* x    = (const float*)d_in[0];
    const int*   mask = (const int*)d_in[1];
    const float* ts   = (const float*)d_in[2];
    const float* it0  = (const float*)d_in[3];
    const float* w_ih = (const float*)d_in[4];
    const float* w_hh = (const float*)d_in[5];
    const float* b_ih = (const float*)d_in[6];
    const float* b_hh = (const float*)d_in[7];
    const float* idw  = (const float*)d_in[8];
    const float* idb  = (const float*)d_in[9];
    const float* hdw  = (const float*)d_in[10];
    const float* hdb  = (const float*)d_in[11];
    float* out = (float*)d_out;

    // Workspace layout (bytes)
    char* ws = (char*)d_ws;
    float* xf   = (float*)(ws);                              // 33554432 B
    float* tdlv = (float*)(ws + 33554432);                   // 262144 B
    float* mean = (float*)(ws + 33816576);                   // 32768 B
    unsigned long long* hx = (unsigned long long*)(ws + 33849344); // 2*B*H u64

    // d_out used as scratch before the RNN overwrites it entirely:
    float* ffill  = out;
    float* idelta = out + (size_t)B * T * D;

    // zero tag words each launch (replay safety)
    hipMemsetAsync(hx, 0, (size_t)(2 * B * H) * 8, stream);

    prep_scan<<<dim3(B, 2), 64, 0, stream>>>(x, mask, ts, it0, ffill, idelta, mean, tdlv);
    fill_kernel<<<(B * T) / ROWS, 256, 0, stream>>>(x, mask, ffill, idelta, mean, idw, idb, xf);
    rnn_kernel<<<NG * GK, 1024, 0, stream>>>(xf, tdlv, w_ih, w_hh, b_ih, b_hh, hdw, hdb,
                                             hx, out);
}

// Round 6
// 1898.444 us; speedup vs baseline: 1.1695x; 1.1695x over previous
//
#include <hip/hip_runtime.h>

// Problem constants
constexpr int B = 64, T = 1024, D = 128, H = 256;
// RNN partition: 64 groups (1 batch each) x 4 blocks of 512 threads.
// Each block owns 64 units; 8 lanes (k-chunks) per unit -> 144 weight floats/thread.
constexpr int NG = 64;   // groups
constexpr int GK = 4;    // blocks per group
constexpr int UO = 64;   // hidden units owned per block
constexpr int CS = 40;   // hdec chunk stride in floats (32 data + 8 skew; 16B-aligned)

// Force a value to stay register-resident: the asm output cannot be
// rematerialized from memory, so the allocator must keep it live.
#define KEEPV(x) asm volatile("" : "+v"(x))

__device__ __forceinline__ float sigmoidf_(float v) {
    return 1.f / (1.f + __expf(-v));
}
__device__ __forceinline__ float tanhf_(float v) {
    float e2 = __expf(2.f * v);
    return 1.f - 2.f / (e2 + 1.f);
}

// ---------------- P1: per-(b,d) scan over t (prefetch-unrolled) ----------------
__global__ __launch_bounds__(64) void prep_scan(
    const float* __restrict__ x, const int* __restrict__ mask,
    const float* __restrict__ ts, const float* __restrict__ it0,
    float* __restrict__ ffill, float* __restrict__ idelta,
    float* __restrict__ mean, float* __restrict__ tdlv)
{
    const int b = blockIdx.x;
    const int d = blockIdx.y * 64 + threadIdx.x;
    float prev_x = 0.f, prev_td = 0.f, osum = 0.f, mcnt = 0.f;
    float prev_ts = it0[b];               // init_time is (1,B) -> flat[b]
    const int baseT = b * T;
    constexpr int U = 16;
    for (int t0 = 0; t0 < T; t0 += U) {
        float xv[U]; int mv[U]; float tsv[U];
        #pragma unroll
        for (int u = 0; u < U; ++u) {
            const int idx = (baseT + t0 + u) * D + d;
            xv[u] = x[idx];
            mv[u] = mask[idx];
        }
        #pragma unroll
        for (int u = 0; u < U; ++u) tsv[u] = ts[baseT + t0 + u];
        #pragma unroll
        for (int u = 0; u < U; ++u) {
            const float td = tsv[u] - prev_ts;
            prev_ts = tsv[u];
            const int idx = (baseT + t0 + u) * D + d;
            if (!mv[u]) { prev_x = xv[u]; osum += xv[u]; } else { mcnt += 1.f; }
            prev_td += td;
            ffill[idx]  = prev_x;
            idelta[idx] = prev_td;
            if (!mv[u]) prev_td = 0.f;
            if (d == 0) tdlv[baseT + t0 + u] = logf(fminf(fmaxf(td, 0.f), 1000.f));
        }
    }
    mean[b * D + d] = osum / fmaxf(mcnt, 1.f);
}

// ---------------- P2: imputation matvec ----------------
constexpr int ROWS = 64;   // (b,t) rows per block
__global__ __launch_bounds__(256) void fill_kernel(
    const float* __restrict__ x, const int* __restrict__ mask,
    const float* __restrict__ ffill, const float* __restrict__ idelta,
    const float* __restrict__ mean, const float* __restrict__ idw,
    const float* __restrict__ idb, float* __restrict__ xf)
{
    __shared__ float widw[128 * 129];   // padded: conflict-free
    __shared__ float ide[2][128];
    const int tid = threadIdx.x;
    for (int i = tid; i < 128 * 128; i += 256)
        widw[(i >> 7) * 129 + (i & 127)] = idw[i];
    __syncthreads();
    const int p = tid >> 7, d = tid & 127;
    const float bias = idb[d];
    const int row0 = blockIdx.x * ROWS;
    for (int r = 0; r < ROWS; r += 2) {
        const int rowp = row0 + r + p;    // b*T + t
        const int idx = rowp * D + d;
        ide[p][d] = fminf(fmaxf(idelta[idx] - 1.f, 0.f), 1000.f);
        __syncthreads();
        float acc = bias;
        #pragma unroll
        for (int k = 0; k < 128; ++k)
            acc = fmaf(ide[p][k], widw[d * 129 + k], acc);
        float fw = __expf(-fmaxf(acc, 0.f));
        float filled = ffill[idx] * fw + (1.f - fw) * mean[(rowp >> 10) * D + d];
        xf[idx] = mask[idx] ? filled : x[idx];
        __syncthreads();
    }
}

// ---------------- P3: persistent grouped GRU-D recurrence ----------------
// 64 independent groups (1 batch each) of 4 blocks x 512 threads. Fence-free
// tagged 64-bit LLC exchange (tag = step+1 | f32 bits), parity double-buffered.
// One barrier per step; hdec skew-strided (CS=40) -> 0 bank conflicts (R4).
// Weights pinned in VGPRs via KEEPV; waves_per_eu pinned to 2 (256-VGPR budget).
__global__ __launch_bounds__(512)
__attribute__((amdgpu_waves_per_eu(2, 2)))
void rnn_kernel(
    const float* __restrict__ xf, const float* __restrict__ tdlv,
    const float* __restrict__ w_ih, const float* __restrict__ w_hh,
    const float* __restrict__ b_ih, const float* __restrict__ b_hh,
    const float* __restrict__ hdw, const float* __restrict__ hdb,
    unsigned long long* __restrict__ hx, float* __restrict__ out)
{
    const int tid = threadIdx.x;
    const int g  = blockIdx.x & (NG - 1);   // group = batch
    const int kb = blockIdx.x >> 6;         // owns units [kb*64, kb*64+64)
    const int u_loc = tid >> 3;             // 0..63
    const int kc = tid & 7;                 // k-chunk 0..7
    const int row = kb * UO + u_loc;        // owned hidden unit
    const int b = g;                        // batch

    // Weight-stationary register slices: gh chunk = 32, gi chunk = 16
    float whr[32], whz[32], whn[32];
    #pragma unroll
    for (int j = 0; j < 32; ++j) {
        whr[j] = w_hh[(row        ) * H + kc * 32 + j];
        whz[j] = w_hh[(row +     H) * H + kc * 32 + j];
        whn[j] = w_hh[(row + 2 * H) * H + kc * 32 + j];
    }
    float wir[16], wiz[16], win_[16];
    #pragma unroll
    for (int j = 0; j < 16; ++j) {
        wir[j]  = w_ih[(row        ) * D + kc * 16 + j];
        wiz[j]  = w_ih[(row +     H) * D + kc * 16 + j];
        win_[j] = w_ih[(row + 2 * H) * D + kc * 16 + j];
    }
    // Pin all weight values in VGPRs (non-rematerializable past this point).
    #pragma unroll
    for (int j = 0; j < 32; ++j) { KEEPV(whr[j]); KEEPV(whz[j]); KEEPV(whn[j]); }
    #pragma unroll
    for (int j = 0; j < 16; ++j) { KEEPV(wir[j]); KEEPV(wiz[j]); KEEPV(win_[j]); }

    // Staging role: threads 0..255 stage unit k = tid
    const bool stager = (tid < H);
    const bool ownk = stager && ((tid >> 6) == kb);
    const float hdwk = stager ? hdw[tid] : 0.f;
    const float hdbk = stager ? hdb[tid] : 0.f;
    const float hdwo = hdw[row];            // decay params for owned unit
    const float hdbo = hdb[row];
    float br = 0.f, bz = 0.f, bnx = 0.f, bnh = 0.f;
    if (kc == 0) {
        br  = b_ih[row] + b_hh[row];
        bz  = b_ih[H + row] + b_hh[H + row];
        bnx = b_ih[2 * H + row];
        bnh = b_hh[2 * H + row];
    }

    __shared__ float hdec[2][8 * CS];   // decayed h, parity buffered, skewed
    for (int i = tid; i < 2 * 8 * CS; i += 512)
        ((float*)hdec)[i] = 0.f;        // h0 = 0 (decayed 0 is 0)
    __syncthreads();

    const float* tdlb = tdlv + b * T;

    for (int t = 0; t < T; ++t) {
        const int par = t & 1;

        // ---- (a) prefetch-probe the remote tag word (hide under gi) ----
        const bool need = (t > 0) && stager && !ownk;
        const unsigned long long* slot =
            hx + (size_t)((t - 1) & 1) * (B * H) + b * H + tid;
        unsigned long long v = 0;
        if (need)
            v = __hip_atomic_load(slot, __ATOMIC_RELAXED, __HIP_MEMORY_SCOPE_AGENT);

        // ---- (b) gi partials: independent of h ----
        const float4* xp4 = (const float4*)(xf + (size_t)(b * T + t) * D + kc * 16);
        float a0 = 0.f, a1 = 0.f, a2 = 0.f;
        #pragma unroll
        for (int i = 0; i < 4; ++i) {
            float4 xq = xp4[i];
            a0 = fmaf(wir[4*i  ], xq.x, a0); a1 = fmaf(wiz[4*i  ], xq.x, a1); a2 = fmaf(win_[4*i  ], xq.x, a2);
            a0 = fmaf(wir[4*i+1], xq.y, a0); a1 = fmaf(wiz[4*i+1], xq.y, a1); a2 = fmaf(win_[4*i+1], xq.y, a2);
            a0 = fmaf(wir[4*i+2], xq.z, a0); a1 = fmaf(wiz[4*i+2], xq.z, a1); a2 = fmaf(win_[4*i+2], xq.z, a2);
            a0 = fmaf(wir[4*i+3], xq.w, a0); a1 = fmaf(wiz[4*i+3], xq.w, a1); a2 = fmaf(win_[4*i+3], xq.w, a2);
        }

        // ---- (c) finish poll + stage decayed remote h into LDS ----
        if (need) {
            while ((unsigned)(v >> 32) != (unsigned)t)
                v = __hip_atomic_load(slot, __ATOMIC_RELAXED, __HIP_MEMORY_SCOPE_AGENT);
            float hv = __uint_as_float((unsigned)v);
            float dec = __expf(-fmaxf(tdlb[t] * hdwk + hdbk, 0.f));
            hdec[par][(tid >> 5) * CS + (tid & 31)] = hv * dec;
        }
        __syncthreads();

        // ---- (d) gh partials from LDS (skewed chunks: conflict-free) ----
        float a3 = 0.f;
        const float4* hp4 = (const float4*)(&hdec[par][kc * CS]);
        #pragma unroll
        for (int i = 0; i < 8; ++i) {
            float4 hq = hp4[i];
            a0 = fmaf(whr[4*i  ], hq.x, a0); a1 = fmaf(whz[4*i  ], hq.x, a1); a3 = fmaf(whn[4*i  ], hq.x, a3);
            a0 = fmaf(whr[4*i+1], hq.y, a0); a1 = fmaf(whz[4*i+1], hq.y, a1); a3 = fmaf(whn[4*i+1], hq.y, a3);
            a0 = fmaf(whr[4*i+2], hq.z, a0); a1 = fmaf(whz[4*i+2], hq.z, a1); a3 = fmaf(whn[4*i+2], hq.z, a3);
            a0 = fmaf(whr[4*i+3], hq.w, a0); a1 = fmaf(whz[4*i+3], hq.w, a1); a3 = fmaf(whn[4*i+3], hq.w, a3);
        }

        // ---- (e) butterfly reduce over the 8 k-chunk lanes ----
        #pragma unroll
        for (int m = 1; m < 8; m <<= 1) {
            a0 += __shfl_xor(a0, m, 64);
            a1 += __shfl_xor(a1, m, 64);
            a2 += __shfl_xor(a2, m, 64);
            a3 += __shfl_xor(a3, m, 64);
        }

        // ---- (f) owner-lane epilogue: hnew, publish first, then stores ----
        if (kc == 0) {
            float hd = hdec[par][(row >> 5) * CS + (row & 31)];
            float r = sigmoidf_(a0 + br);
            float z = sigmoidf_(a1 + bz);
            float n = tanhf_(a2 + bnx + r * (a3 + bnh));
            float hnew = (1.f - z) * n + z * hd;
            // publish to LLC (tag = t+1) -- first, so the store leaves now
            __hip_atomic_store(hx + (size_t)par * (B * H) + b * H + row,
                               (((unsigned long long)(unsigned)(t + 1)) << 32) |
                               (unsigned long long)__float_as_uint(hnew),
                               __ATOMIC_RELAXED, __HIP_MEMORY_SCOPE_AGENT);
            // pre-stage own unit's decayed h for step t+1 (readers of
            // hdec[par^1] only run after next step's barrier)
            if (t + 1 < T) {
                float dec = __expf(-fmaxf(tdlb[t + 1] * hdwo + hdbo, 0.f));
                hdec[par ^ 1][(row >> 5) * CS + (row & 31)] = hnew * dec;
            }
            out[(size_t)(b * T + t) * H + row] = hnew;
            if (t == T - 1)
                out[(size_t)B * T * H + b * H + row] = hnew;
        }
        // no end-of-step barrier: parity buffering + next step's barrier
        // order all hdec writes before their reads.
    }
}

extern "C" void kernel_launch(void* const* d_in, const int* in_sizes, int n_in,
                              void* d_out, int out_size, void* d_ws, size_t ws_size,
                              hipStream_t stream) {
    (void)in_sizes; (void)n_in; (void)out_size; (void)ws_size;
    const float* x    = (const float*)d_in[0];
    const int*   mask = (const int*)d_in[1];
    const float* ts   = (const float*)d_in[2];
    const float* it0  = (const float*)d_in[3];
    const float* w_ih = (const float*)d_in[4];
    const float* w_hh = (const float*)d_in[5];
    const float* b_ih = (const float*)d_in[6];
    const float* b_hh = (const float*)d_in[7];
    const float* idw  = (const float*)d_in[8];
    const float* idb  = (const float*)d_in[9];
    const float* hdw  = (const float*)d_in[10];
    const float* hdb  = (const float*)d_in[11];
    float* out = (float*)d_out;

    // Workspace layout (bytes)
    char* ws = (char*)d_ws;
    float* xf   = (float*)(ws);                              // 33554432 B
    float* tdlv = (float*)(ws + 33554432);                   // 262144 B
    float* mean = (float*)(ws + 33816576);                   // 32768 B
    unsigned long long* hx = (unsigned long long*)(ws + 33849344); // 2*B*H u64

    // d_out used as scratch before the RNN overwrites it entirely:
    float* ffill  = out;
    float* idelta = out + (size_t)B * T * D;

    // zero tag words each launch (replay safety)
    hipMemsetAsync(hx, 0, (size_t)(2 * B * H) * 8, stream);

    prep_scan<<<dim3(B, 2), 64, 0, stream>>>(x, mask, ts, it0, ffill, idelta, mean, tdlv);
    fill_kernel<<<(B * T) / ROWS, 256, 0, stream>>>(x, mask, ffill, idelta, mean, idw, idb, xf);
    rnn_kernel<<<NG * GK, 512, 0, stream>>>(xf, tdlv, w_ih, w_hh, b_ih, b_hh, hdw, hdb,
                                            hx, out);
}